// Round 2
// baseline (628.133 us; speedup 1.0000x reference)
//
#include <hip/hip_runtime.h>
#include <math.h>

#define N_USERS 8192
#define N_ITEMS 4096
#define BATCH   8192
#define NTILE_I 64                 // 64-wide item tiles
#define NTILE_U2 64                // 128-wide user tiles
#define NTILES  (NTILE_I * NTILE_U2)   // 4096 tiles of 64 items x 128 users
#define FGRID   512
#define FTHR    512

// LDS: phase1 transpose tile / phase2 reduce scratch / phase3 ub stage (union)
union SMem {
    float  tr[128][65];            // 33280 B: [user][item] tile
    float4 ubs[N_USERS / 4];       // 32768 B
    struct { float ss[8][64]; float sc[8][64]; } fin;   // 4096 B
};

// ---------------------------------------------------------------------------
// Device-scope grid barrier. Correctness relies on all FGRID blocks being
// co-resident: __launch_bounds__(512,4) => VGPR<=128 => >=2 blocks/CU
// => capacity >= 512 = grid. bar[0]=count, bar[1]=generation (memset to 0
// on the stream before launch, re-done every graph replay).
// ---------------------------------------------------------------------------
__device__ __forceinline__ void gridbar(unsigned* bar, unsigned nblk) {
    __syncthreads();
    if (threadIdx.x == 0) {
        __threadfence();   // publish this block's global writes (agent scope)
        unsigned g = __hip_atomic_load(&bar[1], __ATOMIC_RELAXED, __HIP_MEMORY_SCOPE_AGENT);
        unsigned a = __hip_atomic_fetch_add(&bar[0], 1u, __ATOMIC_ACQ_REL, __HIP_MEMORY_SCOPE_AGENT) + 1;
        if (a == nblk) {
            __hip_atomic_store(&bar[0], 0u, __ATOMIC_RELAXED, __HIP_MEMORY_SCOPE_AGENT);
            __hip_atomic_store(&bar[1], g + 1u, __ATOMIC_RELEASE, __HIP_MEMORY_SCOPE_AGENT);
        } else {
            while (__hip_atomic_load(&bar[1], __ATOMIC_ACQUIRE, __HIP_MEMORY_SCOPE_AGENT) == g) {
                __builtin_amdgcn_s_sleep(2);
            }
        }
        __threadfence();   // invalidate caches before reading others' writes
    }
    __syncthreads();
}

// ---------------------------------------------------------------------------
// Fused pipeline: phase1 transpose+partials -> bar -> phase2 ub -> bar ->
// phase3 batch dot products. One dispatch = full diagnostic visibility.
// ---------------------------------------------------------------------------
__global__ __launch_bounds__(FTHR, 4) void k_fused(const float* __restrict__ R,
                                                   unsigned char* __restrict__ AT,
                                                   float* __restrict__ psum,
                                                   float* __restrict__ pcnt,
                                                   float* __restrict__ ub,
                                                   unsigned* __restrict__ bar,
                                                   const float* __restrict__ S,
                                                   const int* __restrict__ user,
                                                   const int* __restrict__ item,
                                                   const float* __restrict__ ubias,
                                                   const float* __restrict__ ibias,
                                                   const float* __restrict__ gbias,
                                                   float* __restrict__ out) {
    __shared__ SMem sm;
    const int tid = threadIdx.x;
    const int blk = blockIdx.x;

    // ---------------- phase 1: transpose + per-user partial sums -----------
    // 4096 tiles (64 items x 128 users), 8 per block.
    {
        const int tx = tid & 15;          // float4 column within tile
        const int ty = tid >> 4;          // 0..31: user row group
        const int x4 = tx * 4;
        for (int it = 0; it < 8; ++it) {
            const int t = blk * 8 + it;
            const int bx = t & 63;        // item tile
            const int by = t >> 6;        // user tile (128 users)
            const int colBase = bx * 64;
            const int rowBase = by * 128;

            float s[4], c[4];
            #pragma unroll
            for (int k = 0; k < 4; ++k) {
                const int y = ty + 32 * k;
                float4 v = *(const float4*)(R + (size_t)(rowBase + y) * N_ITEMS + colBase + x4);
                sm.tr[y][x4 + 0] = v.x;
                sm.tr[y][x4 + 1] = v.y;
                sm.tr[y][x4 + 2] = v.z;
                sm.tr[y][x4 + 3] = v.w;
                s[k] = v.x + v.y + v.z + v.w;
                c[k] = (v.x != 0.f) + (v.y != 0.f) + (v.z != 0.f) + (v.w != 0.f);
            }
            // reduce the 16 tx lanes of each (ty,k) row group
            #pragma unroll
            for (int k = 0; k < 4; ++k) {
                #pragma unroll
                for (int off = 8; off; off >>= 1) {
                    s[k] += __shfl_down(s[k], off, 16);
                    c[k] += __shfl_down(c[k], off, 16);
                }
            }
            if (tx == 0) {
                #pragma unroll
                for (int k = 0; k < 4; ++k) {
                    const int u = rowBase + ty + 32 * k;
                    psum[(size_t)bx * N_USERS + u] = s[k];
                    pcnt[(size_t)bx * N_USERS + u] = c[k];
                }
            }
            __syncthreads();

            // store: 64 item rows x 8 int4 chunks = 512 stores, 1/thread.
            // 8 chunks x 16 B = 128 B per item row: full-line writes.
            const int il = tid >> 3;      // item row 0..63
            const int ch = tid & 7;       // 16-user chunk 0..7
            union { unsigned char b[16]; int4 v; } w;
            #pragma unroll
            for (int e = 0; e < 16; ++e) {
                w.b[e] = (unsigned char)(int)sm.tr[ch * 16 + e][il];
            }
            *(int4*)(AT + (size_t)(colBase + il) * N_USERS + rowBase + ch * 16) = w.v;
            __syncthreads();
        }
    }
    gridbar(bar, FGRID);

    // ---------------- phase 2: ub[u] from 64 tile-partials -----------------
    if (blk < 128) {
        const int ul  = tid & 63;
        const int seg = tid >> 6;         // 0..7, 8 tiles each
        const int u = blk * 64 + ul;
        float s = 0.f, c = 0.f;
        #pragma unroll
        for (int k = 0; k < 8; ++k) {
            const int t = seg * 8 + k;
            s += psum[(size_t)t * N_USERS + u];
            c += pcnt[(size_t)t * N_USERS + u];
        }
        sm.fin.ss[seg][ul] = s;
        sm.fin.sc[seg][ul] = c;
        __syncthreads();
        if (tid < 64) {
            s = 0.f; c = 0.f;
            #pragma unroll
            for (int k = 0; k < 8; ++k) { s += sm.fin.ss[k][ul]; c += sm.fin.sc[k][ul]; }
            ub[u] = (c > 0.f) ? s / fmaxf(c, 1.f) : 0.f;
        }
    }
    gridbar(bar, FGRID);

    // ---------------- phase 3: out[b] = sigmoid(dot + biases) * 5 ----------
    #pragma unroll
    for (int t = 0; t < 4; ++t) {
        sm.ubs[t * FTHR + tid] = ((const float4*)ub)[t * FTHR + tid];
    }
    __syncthreads();

    const int wave = tid >> 6;
    const int lane = tid & 63;
    #pragma unroll
    for (int g = 0; g < 2; ++g) {
        const int b = (blk * 2 + g) * 8 + wave;
        const int su = user[b];
        const int j  = item[b];
        const float4* srow = (const float4*)(S + (size_t)su * N_USERS);
        const uint2*  arow = (const uint2*)(AT + (size_t)j * N_USERS);

        float acc = 0.f;
        #pragma unroll 4
        for (int i = 0; i < 16; ++i) {
            const int idx = i * 64 + lane;       // unit = 8 users
            uint2  a  = arow[idx];
            float4 s0 = srow[2 * idx + 0];
            float4 s1 = srow[2 * idx + 1];
            float4 u0 = sm.ubs[2 * idx + 0];
            float4 u1 = sm.ubs[2 * idx + 1];
            acc += s0.x * ((float)( a.x        & 0xffu) - u0.x);
            acc += s0.y * ((float)((a.x >>  8) & 0xffu) - u0.y);
            acc += s0.z * ((float)((a.x >> 16) & 0xffu) - u0.z);
            acc += s0.w * ((float)( a.x >> 24         ) - u0.w);
            acc += s1.x * ((float)( a.y        & 0xffu) - u1.x);
            acc += s1.y * ((float)((a.y >>  8) & 0xffu) - u1.y);
            acc += s1.z * ((float)((a.y >> 16) & 0xffu) - u1.z);
            acc += s1.w * ((float)( a.y >> 24         ) - u1.w);
        }
        #pragma unroll
        for (int off = 32; off; off >>= 1) acc += __shfl_down(acc, off);

        if (lane == 0) {
            float score = acc + ubias[su] + ibias[j] + gbias[0];
            out[b] = 5.f / (1.f + expf(-score));
        }
    }
}

// ---------------------------------------------------------------------------
// Fallback path (ws too small): original 3-pass f32 scheme.
// ---------------------------------------------------------------------------
__global__ __launch_bounds__(256) void k_ubfix(const float* __restrict__ R,
                                               float* __restrict__ ub) {
    const int wave = threadIdx.x >> 6;
    const int lane = threadIdx.x & 63;
    const int u = blockIdx.x * 4 + wave;
    const float4* row4 = (const float4*)(R + (size_t)u * N_ITEMS);
    float s = 0.f, c = 0.f;
    #pragma unroll
    for (int i = 0; i < 16; ++i) {
        float4 v = row4[i * 64 + lane];
        s += v.x + v.y + v.z + v.w;
        c += (v.x != 0.f) + (v.y != 0.f) + (v.z != 0.f) + (v.w != 0.f);
    }
    #pragma unroll
    for (int off = 32; off; off >>= 1) {
        s += __shfl_down(s, off);
        c += __shfl_down(c, off);
    }
    if (lane == 0)
        ub[u] = (c > 0.f) ? s / fmaxf(c, 1.f) : 0.f;
}

__global__ __launch_bounds__(256) void k_direct(const float* __restrict__ S,
                                                const float* __restrict__ R,
                                                const float* __restrict__ ub,
                                                const int* __restrict__ user,
                                                const int* __restrict__ item,
                                                const float* __restrict__ ubias,
                                                const float* __restrict__ ibias,
                                                const float* __restrict__ gbias,
                                                float* __restrict__ out) {
    const int b = blockIdx.x;
    const int su = user[b];
    const int j  = item[b];
    const float* srow = S + (size_t)su * N_USERS;
    float acc = 0.f;
    for (int u = threadIdx.x; u < N_USERS; u += 256) {
        acc += srow[u] * (R[(size_t)u * N_ITEMS + j] - ub[u]);
    }
    for (int off = 32; off; off >>= 1) acc += __shfl_down(acc, off);
    __shared__ float sa[4];
    const int lane = threadIdx.x & 63, w = threadIdx.x >> 6;
    if (lane == 0) sa[w] = acc;
    __syncthreads();
    if (threadIdx.x == 0) {
        float score = sa[0] + sa[1] + sa[2] + sa[3]
                    + ubias[su] + ibias[j] + gbias[0];
        out[b] = 5.f / (1.f + expf(-score));
    }
}

extern "C" void kernel_launch(void* const* d_in, const int* in_sizes, int n_in,
                              void* d_out, int out_size, void* d_ws, size_t ws_size,
                              hipStream_t stream) {
    const int*   user  = (const int*)d_in[0];
    const int*   item  = (const int*)d_in[1];
    const float* R     = (const float*)d_in[2];   // [N_USERS][N_ITEMS] f32
    const float* S     = (const float*)d_in[3];   // [N_USERS][N_USERS] f32
    const float* ubias = (const float*)d_in[4];
    const float* ibias = (const float*)d_in[5];
    const float* gbias = (const float*)d_in[6];
    float* out = (float*)d_out;

    // ws layout:
    //   [0, 32KB)            ub[N_USERS] f32
    //   [48KB, 48KB+16B)     grid-barrier state (count, generation)
    //   [64KB, 64KB+2MB)     psum[64][N_USERS] f32
    //   [64KB+2MB, +2MB)     pcnt[64][N_USERS] f32
    //   [8MB, 8MB+32MB)      AT[N_ITEMS][N_USERS] uint8
    float* ub       = (float*)d_ws;
    unsigned* bar   = (unsigned*)((char*)d_ws + (48u << 10));
    float* psum     = (float*)((char*)d_ws + (64u << 10));
    float* pcnt     = (float*)((char*)d_ws + (64u << 10) + (size_t)64 * N_USERS * 4);
    unsigned char* AT = (unsigned char*)((char*)d_ws + (8u << 20));
    const size_t need = (8u << 20) + (size_t)N_ITEMS * N_USERS;

    if (ws_size >= need) {
        hipMemsetAsync(bar, 0, 16, stream);   // zero barrier state (poisoned)
        k_fused<<<FGRID, FTHR, 0, stream>>>(R, AT, psum, pcnt, ub, bar,
                                            S, user, item, ubias, ibias, gbias, out);
    } else {
        k_ubfix<<<N_USERS / 4, 256, 0, stream>>>(R, ub);
        k_direct<<<BATCH, 256, 0, stream>>>(S, R, ub, user, item, ubias, ibias, gbias, out);
    }
}

// Round 3
// 451.952 us; speedup vs baseline: 1.3898x; 1.3898x over previous
//
#include <hip/hip_runtime.h>
#include <math.h>

#define N_USERS 8192
#define N_ITEMS 4096
#define BATCH   8192

// ---------------------------------------------------------------------------
// K_A: fused transpose + per-row partial sums, 64-item x 128-user tiles.
//   AT[j][u] = (uint8)R[u][j]              (exact: R in {0..5})
//   gsum[u] += sum of R[u][tile cols]      (atomic; exact ints in f32,
//   gcnt[u] += nnz of same                  so add order is bit-irrelevant)
// 128-user tiles => every AT store covers a full 128-B line.
// grid (64, 64), block 512.
// ---------------------------------------------------------------------------
__global__ __launch_bounds__(512) void k_trans(const float* __restrict__ R,
                                               unsigned char* __restrict__ AT,
                                               float* __restrict__ gsum,
                                               float* __restrict__ gcnt) {
    __shared__ float tr[128][65];
    const int colBase = blockIdx.x * 64;    // item dim
    const int rowBase = blockIdx.y * 128;   // user dim
    const int tid = threadIdx.x;
    const int tx = tid & 15;                // float4 column
    const int ty = tid >> 4;                // 0..31 user row group
    const int x4 = tx * 4;

    float s[4], c[4];
    #pragma unroll
    for (int k = 0; k < 4; ++k) {
        const int y = ty + 32 * k;
        float4 v = *(const float4*)(R + (size_t)(rowBase + y) * N_ITEMS + colBase + x4);
        tr[y][x4 + 0] = v.x;
        tr[y][x4 + 1] = v.y;
        tr[y][x4 + 2] = v.z;
        tr[y][x4 + 3] = v.w;
        s[k] = v.x + v.y + v.z + v.w;
        c[k] = (v.x != 0.f) + (v.y != 0.f) + (v.z != 0.f) + (v.w != 0.f);
    }
    // reduce the 16 tx lanes of each (ty,k) row group (shfl width 16, in-wave)
    #pragma unroll
    for (int k = 0; k < 4; ++k) {
        #pragma unroll
        for (int off = 8; off; off >>= 1) {
            s[k] += __shfl_down(s[k], off, 16);
            c[k] += __shfl_down(c[k], off, 16);
        }
    }
    if (tx == 0) {
        #pragma unroll
        for (int k = 0; k < 4; ++k) {
            const int u = rowBase + ty + 32 * k;
            atomicAdd(&gsum[u], s[k]);
            atomicAdd(&gcnt[u], c[k]);
        }
    }
    __syncthreads();

    // store: 64 item rows x 8 int4 chunks (16 users) = 512 stores, 1/thread.
    // lanes 0..7 of each 8-lane group write one contiguous 128-B AT line.
    const int il = tid >> 3;                // item row 0..63
    const int ch = tid & 7;                 // 16-user chunk
    union { unsigned char b[16]; int4 v; } w;
    #pragma unroll
    for (int e = 0; e < 16; ++e) {
        w.b[e] = (unsigned char)(int)tr[ch * 16 + e][il];
    }
    *(int4*)(AT + (size_t)(colBase + il) * N_USERS + rowBase + ch * 16) = w.v;
}

// ---------------------------------------------------------------------------
// K_B: one WAVE per batch element, 8 waves (512 thr) per block.
//   out[b] = sigmoid( dot(S[user[b]], (float)AT[item[b]] - ub) + biases ) * 5
// ub is computed during the LDS stage from gsum/gcnt (exact ints, IEEE
// divide => bit-identical to the old separate k_fin). Hot loop unchanged
// from the verified round-1 version (same summation order => absmax 0).
// ---------------------------------------------------------------------------
__global__ __launch_bounds__(512, 6) void k_main(const float* __restrict__ S,
                                                 const unsigned char* __restrict__ AT,
                                                 const float* __restrict__ gsum,
                                                 const float* __restrict__ gcnt,
                                                 const int* __restrict__ user,
                                                 const int* __restrict__ item,
                                                 const float* __restrict__ ubias,
                                                 const float* __restrict__ ibias,
                                                 const float* __restrict__ gbias,
                                                 float* __restrict__ out) {
    __shared__ float4 ubs[N_USERS / 4];   // 32 KiB
    #pragma unroll
    for (int t = 0; t < 4; ++t) {
        const int p = t * 512 + threadIdx.x;
        float4 sv = ((const float4*)gsum)[p];
        float4 cv = ((const float4*)gcnt)[p];
        float4 u;
        u.x = (cv.x > 0.f) ? sv.x / cv.x : 0.f;
        u.y = (cv.y > 0.f) ? sv.y / cv.y : 0.f;
        u.z = (cv.z > 0.f) ? sv.z / cv.z : 0.f;
        u.w = (cv.w > 0.f) ? sv.w / cv.w : 0.f;
        ubs[p] = u;
    }
    __syncthreads();

    const int wave = threadIdx.x >> 6;
    const int lane = threadIdx.x & 63;
    const int b = blockIdx.x * 8 + wave;
    const int su = user[b];
    const int j  = item[b];
    const float4* srow = (const float4*)(S + (size_t)su * N_USERS);
    const uint2*  arow = (const uint2*)(AT + (size_t)j * N_USERS);

    float acc = 0.f;
    #pragma unroll 4
    for (int i = 0; i < 16; ++i) {
        const int idx = i * 64 + lane;       // unit = 8 users
        uint2  a  = arow[idx];
        float4 s0 = srow[2 * idx + 0];
        float4 s1 = srow[2 * idx + 1];
        float4 u0 = ubs[2 * idx + 0];
        float4 u1 = ubs[2 * idx + 1];
        acc += s0.x * ((float)( a.x        & 0xffu) - u0.x);
        acc += s0.y * ((float)((a.x >>  8) & 0xffu) - u0.y);
        acc += s0.z * ((float)((a.x >> 16) & 0xffu) - u0.z);
        acc += s0.w * ((float)( a.x >> 24         ) - u0.w);
        acc += s1.x * ((float)( a.y        & 0xffu) - u1.x);
        acc += s1.y * ((float)((a.y >>  8) & 0xffu) - u1.y);
        acc += s1.z * ((float)((a.y >> 16) & 0xffu) - u1.z);
        acc += s1.w * ((float)( a.y >> 24         ) - u1.w);
    }
    #pragma unroll
    for (int off = 32; off; off >>= 1) acc += __shfl_down(acc, off);

    if (lane == 0) {
        float score = acc + ubias[su] + ibias[j] + gbias[0];
        out[b] = 5.f / (1.f + expf(-score));
    }
}

// ---------------------------------------------------------------------------
// Fallback path (ws too small): original 3-pass f32 scheme.
// ---------------------------------------------------------------------------
__global__ __launch_bounds__(256) void k_ubfix(const float* __restrict__ R,
                                               float* __restrict__ ub) {
    const int wave = threadIdx.x >> 6;
    const int lane = threadIdx.x & 63;
    const int u = blockIdx.x * 4 + wave;
    const float4* row4 = (const float4*)(R + (size_t)u * N_ITEMS);
    float s = 0.f, c = 0.f;
    #pragma unroll
    for (int i = 0; i < 16; ++i) {
        float4 v = row4[i * 64 + lane];
        s += v.x + v.y + v.z + v.w;
        c += (v.x != 0.f) + (v.y != 0.f) + (v.z != 0.f) + (v.w != 0.f);
    }
    #pragma unroll
    for (int off = 32; off; off >>= 1) {
        s += __shfl_down(s, off);
        c += __shfl_down(c, off);
    }
    if (lane == 0)
        ub[u] = (c > 0.f) ? s / fmaxf(c, 1.f) : 0.f;
}

__global__ __launch_bounds__(256) void k_direct(const float* __restrict__ S,
                                                const float* __restrict__ R,
                                                const float* __restrict__ ub,
                                                const int* __restrict__ user,
                                                const int* __restrict__ item,
                                                const float* __restrict__ ubias,
                                                const float* __restrict__ ibias,
                                                const float* __restrict__ gbias,
                                                float* __restrict__ out) {
    const int b = blockIdx.x;
    const int su = user[b];
    const int j  = item[b];
    const float* srow = S + (size_t)su * N_USERS;
    float acc = 0.f;
    for (int u = threadIdx.x; u < N_USERS; u += 256) {
        acc += srow[u] * (R[(size_t)u * N_ITEMS + j] - ub[u]);
    }
    for (int off = 32; off; off >>= 1) acc += __shfl_down(acc, off);
    __shared__ float sa[4];
    const int lane = threadIdx.x & 63, w = threadIdx.x >> 6;
    if (lane == 0) sa[w] = acc;
    __syncthreads();
    if (threadIdx.x == 0) {
        float score = sa[0] + sa[1] + sa[2] + sa[3]
                    + ubias[su] + ibias[j] + gbias[0];
        out[b] = 5.f / (1.f + expf(-score));
    }
}

extern "C" void kernel_launch(void* const* d_in, const int* in_sizes, int n_in,
                              void* d_out, int out_size, void* d_ws, size_t ws_size,
                              hipStream_t stream) {
    const int*   user  = (const int*)d_in[0];
    const int*   item  = (const int*)d_in[1];
    const float* R     = (const float*)d_in[2];   // [N_USERS][N_ITEMS] f32
    const float* S     = (const float*)d_in[3];   // [N_USERS][N_USERS] f32
    const float* ubias = (const float*)d_in[4];
    const float* ibias = (const float*)d_in[5];
    const float* gbias = (const float*)d_in[6];
    float* out = (float*)d_out;

    // ws layout:
    //   [0, 32KB)            gsum[N_USERS] f32   (atomic accumulators)
    //   [32KB, 64KB)         gcnt[N_USERS] f32
    //   [8MB, 8MB+32MB)      AT[N_ITEMS][N_USERS] uint8
    float* gsum = (float*)d_ws;
    float* gcnt = (float*)((char*)d_ws + (32u << 10));
    unsigned char* AT = (unsigned char*)((char*)d_ws + (8u << 20));
    const size_t need = (8u << 20) + (size_t)N_ITEMS * N_USERS;

    if (ws_size >= need) {
        hipMemsetAsync(d_ws, 0, 64u << 10, stream);   // zero gsum/gcnt
        dim3 tgrid(N_ITEMS / 64, N_USERS / 128);
        k_trans<<<tgrid, 512, 0, stream>>>(R, AT, gsum, gcnt);
        k_main<<<BATCH / 8, 512, 0, stream>>>(S, AT, gsum, gcnt,
                                              user, item, ubias, ibias, gbias, out);
    } else {
        float* ub = (float*)d_ws;
        k_ubfix<<<N_USERS / 4, 256, 0, stream>>>(R, ub);
        k_direct<<<BATCH, 256, 0, stream>>>(S, R, ub, user, item, ubias, ibias, gbias, out);
    }
}

// Round 6
// 451.692 us; speedup vs baseline: 1.3906x; 1.0006x over previous
//
#include <hip/hip_runtime.h>
#include <math.h>

#define N_USERS 8192
#define N_ITEMS 4096
#define BATCH   8192

// ---------------------------------------------------------------------------
// K_A: fused transpose + per-row partial sums, 64-item x 128-user tiles.
//   AT[j][u] = (uint8)R[u][j]              (exact: R in {0..5})
//   gsum[u] += sum of R[u][tile cols]      (atomic; exact small ints in f32,
//   gcnt[u] += nnz of same                  so add order is bit-irrelevant)
// Verbatim the round-3 kernel that ran at 452us overall (passed, absmax 0).
// 128-user tiles => every AT store covers a full 128-B line.
// grid (64, 64), block 512.
// ---------------------------------------------------------------------------
__global__ __launch_bounds__(512) void k_trans(const float* __restrict__ R,
                                               unsigned char* __restrict__ AT,
                                               float* __restrict__ gsum,
                                               float* __restrict__ gcnt) {
    __shared__ float tr[128][65];
    const int colBase = blockIdx.x * 64;    // item dim
    const int rowBase = blockIdx.y * 128;   // user dim
    const int tid = threadIdx.x;
    const int tx = tid & 15;                // float4 column
    const int ty = tid >> 4;                // 0..31 user row group
    const int x4 = tx * 4;

    float s[4], c[4];
    #pragma unroll
    for (int k = 0; k < 4; ++k) {
        const int y = ty + 32 * k;
        float4 v = *(const float4*)(R + (size_t)(rowBase + y) * N_ITEMS + colBase + x4);
        tr[y][x4 + 0] = v.x;
        tr[y][x4 + 1] = v.y;
        tr[y][x4 + 2] = v.z;
        tr[y][x4 + 3] = v.w;
        s[k] = v.x + v.y + v.z + v.w;
        c[k] = (v.x != 0.f) + (v.y != 0.f) + (v.z != 0.f) + (v.w != 0.f);
    }
    // reduce the 16 tx lanes of each (ty,k) row group (shfl width 16, in-wave)
    #pragma unroll
    for (int k = 0; k < 4; ++k) {
        #pragma unroll
        for (int off = 8; off; off >>= 1) {
            s[k] += __shfl_down(s[k], off, 16);
            c[k] += __shfl_down(c[k], off, 16);
        }
    }
    if (tx == 0) {
        #pragma unroll
        for (int k = 0; k < 4; ++k) {
            const int u = rowBase + ty + 32 * k;
            atomicAdd(&gsum[u], s[k]);
            atomicAdd(&gcnt[u], c[k]);
        }
    }
    __syncthreads();

    // store: 64 item rows x 8 int4 chunks (16 users) = 512 stores, 1/thread.
    const int il = tid >> 3;                // item row 0..63
    const int ch = tid & 7;                 // 16-user chunk
    union { unsigned char b[16]; int4 v; } w;
    #pragma unroll
    for (int e = 0; e < 16; ++e) {
        w.b[e] = (unsigned char)(int)tr[ch * 16 + e][il];
    }
    *(int4*)(AT + (size_t)(colBase + il) * N_USERS + rowBase + ch * 16) = w.v;
}

// ---------------------------------------------------------------------------
// K_ub: ub[u] = cnt>0 ? sum/cnt : 0. Tiny (32 blocks, ~2us) but it keeps
// k_main's per-block prologue divide-free and at 32 KB instead of 64 KB
// (the fused-divide variant measured ~10us slower overall in round 3).
// ---------------------------------------------------------------------------
__global__ __launch_bounds__(256) void k_ub(const float* __restrict__ gsum,
                                            const float* __restrict__ gcnt,
                                            float* __restrict__ ub) {
    const int u = blockIdx.x * 256 + threadIdx.x;
    const float s = gsum[u], c = gcnt[u];
    ub[u] = (c > 0.f) ? s / c : 0.f;
}

// ---------------------------------------------------------------------------
// K_B: one WAVE per batch element, 8 waves (512 thr) per block.
//   out[b] = sigmoid( dot(S[user[b]], (float)AT[item[b]] - ub) + biases ) * 5
// Verbatim the round-1 kernel that measured 443us / absmax 0.0:
// ub staged to 32 KiB LDS once per block, 3 VMEM + 2 LDS reads per iter.
// ---------------------------------------------------------------------------
__global__ __launch_bounds__(512, 6) void k_main(const float* __restrict__ S,
                                                 const unsigned char* __restrict__ AT,
                                                 const float* __restrict__ ub,
                                                 const int* __restrict__ user,
                                                 const int* __restrict__ item,
                                                 const float* __restrict__ ubias,
                                                 const float* __restrict__ ibias,
                                                 const float* __restrict__ gbias,
                                                 float* __restrict__ out) {
    __shared__ float4 ubs[N_USERS / 4];   // 32 KiB
    #pragma unroll
    for (int t = 0; t < 4; ++t) {
        ubs[t * 512 + threadIdx.x] = ((const float4*)ub)[t * 512 + threadIdx.x];
    }
    __syncthreads();

    const int wave = threadIdx.x >> 6;
    const int lane = threadIdx.x & 63;
    const int b = blockIdx.x * 8 + wave;
    const int su = user[b];
    const int j  = item[b];
    const float4* srow = (const float4*)(S + (size_t)su * N_USERS);
    const uint2*  arow = (const uint2*)(AT + (size_t)j * N_USERS);

    float acc = 0.f;
    #pragma unroll 4
    for (int i = 0; i < 16; ++i) {
        const int idx = i * 64 + lane;       // unit = 8 users
        uint2  a  = arow[idx];
        float4 s0 = srow[2 * idx + 0];
        float4 s1 = srow[2 * idx + 1];
        float4 u0 = ubs[2 * idx + 0];
        float4 u1 = ubs[2 * idx + 1];
        acc += s0.x * ((float)( a.x        & 0xffu) - u0.x);
        acc += s0.y * ((float)((a.x >>  8) & 0xffu) - u0.y);
        acc += s0.z * ((float)((a.x >> 16) & 0xffu) - u0.z);
        acc += s0.w * ((float)( a.x >> 24         ) - u0.w);
        acc += s1.x * ((float)( a.y        & 0xffu) - u1.x);
        acc += s1.y * ((float)((a.y >>  8) & 0xffu) - u1.y);
        acc += s1.z * ((float)((a.y >> 16) & 0xffu) - u1.z);
        acc += s1.w * ((float)( a.y >> 24         ) - u1.w);
    }
    #pragma unroll
    for (int off = 32; off; off >>= 1) acc += __shfl_down(acc, off);

    if (lane == 0) {
        float score = acc + ubias[su] + ibias[j] + gbias[0];
        out[b] = 5.f / (1.f + expf(-score));
    }
}

// ---------------------------------------------------------------------------
// Fallback path (ws too small): original 3-pass f32 scheme.
// ---------------------------------------------------------------------------
__global__ __launch_bounds__(256) void k_ubfix(const float* __restrict__ R,
                                               float* __restrict__ ub) {
    const int wave = threadIdx.x >> 6;
    const int lane = threadIdx.x & 63;
    const int u = blockIdx.x * 4 + wave;
    const float4* row4 = (const float4*)(R + (size_t)u * N_ITEMS);
    float s = 0.f, c = 0.f;
    #pragma unroll
    for (int i = 0; i < 16; ++i) {
        float4 v = row4[i * 64 + lane];
        s += v.x + v.y + v.z + v.w;
        c += (v.x != 0.f) + (v.y != 0.f) + (v.z != 0.f) + (v.w != 0.f);
    }
    #pragma unroll
    for (int off = 32; off; off >>= 1) {
        s += __shfl_down(s, off);
        c += __shfl_down(c, off);
    }
    if (lane == 0)
        ub[u] = (c > 0.f) ? s / fmaxf(c, 1.f) : 0.f;
}

__global__ __launch_bounds__(256) void k_direct(const float* __restrict__ S,
                                                const float* __restrict__ R,
                                                const float* __restrict__ ub,
                                                const int* __restrict__ user,
                                                const int* __restrict__ item,
                                                const float* __restrict__ ubias,
                                                const float* __restrict__ ibias,
                                                const float* __restrict__ gbias,
                                                float* __restrict__ out) {
    const int b = blockIdx.x;
    const int su = user[b];
    const int j  = item[b];
    const float* srow = S + (size_t)su * N_USERS;
    float acc = 0.f;
    for (int u = threadIdx.x; u < N_USERS; u += 256) {
        acc += srow[u] * (R[(size_t)u * N_ITEMS + j] - ub[u]);
    }
    for (int off = 32; off; off >>= 1) acc += __shfl_down(acc, off);
    __shared__ float sa[4];
    const int lane = threadIdx.x & 63, w = threadIdx.x >> 6;
    if (lane == 0) sa[w] = acc;
    __syncthreads();
    if (threadIdx.x == 0) {
        float score = sa[0] + sa[1] + sa[2] + sa[3]
                    + ubias[su] + ibias[j] + gbias[0];
        out[b] = 5.f / (1.f + expf(-score));
    }
}

extern "C" void kernel_launch(void* const* d_in, const int* in_sizes, int n_in,
                              void* d_out, int out_size, void* d_ws, size_t ws_size,
                              hipStream_t stream) {
    const int*   user  = (const int*)d_in[0];
    const int*   item  = (const int*)d_in[1];
    const float* R     = (const float*)d_in[2];   // [N_USERS][N_ITEMS] f32
    const float* S     = (const float*)d_in[3];   // [N_USERS][N_USERS] f32
    const float* ubias = (const float*)d_in[4];
    const float* ibias = (const float*)d_in[5];
    const float* gbias = (const float*)d_in[6];
    float* out = (float*)d_out;

    // ws layout:
    //   [0, 32KB)            gsum[N_USERS] f32   (atomic accumulators)
    //   [32KB, 64KB)         gcnt[N_USERS] f32
    //   [64KB, 96KB)         ub[N_USERS] f32
    //   [8MB, 8MB+32MB)      AT[N_ITEMS][N_USERS] uint8
    float* gsum = (float*)d_ws;
    float* gcnt = (float*)((char*)d_ws + (32u << 10));
    float* ub   = (float*)((char*)d_ws + (64u << 10));
    unsigned char* AT = (unsigned char*)((char*)d_ws + (8u << 20));
    const size_t need = (8u << 20) + (size_t)N_ITEMS * N_USERS;

    if (ws_size >= need) {
        hipMemsetAsync(d_ws, 0, 64u << 10, stream);   // zero gsum/gcnt
        dim3 tgrid(N_ITEMS / 64, N_USERS / 128);
        k_trans<<<tgrid, 512, 0, stream>>>(R, AT, gsum, gcnt);
        k_ub<<<N_USERS / 256, 256, 0, stream>>>(gsum, gcnt, ub);
        k_main<<<BATCH / 8, 512, 0, stream>>>(S, AT, ub, user, item,
                                              ubias, ibias, gbias, out);
    } else {
        float* ubf = (float*)d_ws;
        k_ubfix<<<N_USERS / 4, 256, 0, stream>>>(R, ubf);
        k_direct<<<BATCH, 256, 0, stream>>>(S, R, ubf, user, item, ubias, ibias, gbias, out);
    }
}

// Round 7
// 442.795 us; speedup vs baseline: 1.4186x; 1.0201x over previous
//
#include <hip/hip_runtime.h>
#include <math.h>

#define N_USERS 8192
#define N_ITEMS 4096
#define BATCH   8192
#define NTILE_I (N_ITEMS / 64)   // 64 item tiles per user stripe

// ---------------------------------------------------------------------------
// K_A: fused transpose + per-row partial sums.
//   AT[j][u] = (uint8)R[u][j]            (exact: R in {0..5})
//   psum[bx][u] = sum of R[u][ colBase .. colBase+63 ]
//   pcnt[bx][u] = nonzero count of same
// grid (NTILE_I, N_USERS/64), block (16,16).
// (Measured best: psum/pcnt partials + separate k_fin beats the atomicAdd
//  variants by ~9us — R1=443.1 vs R3/R6=452.)
// ---------------------------------------------------------------------------
__global__ __launch_bounds__(256) void k_trans(const float* __restrict__ R,
                                               unsigned char* __restrict__ AT,
                                               float* __restrict__ psum,
                                               float* __restrict__ pcnt) {
    __shared__ float lds[64][65];
    const int colBase = blockIdx.x * 64;   // item dim
    const int rowBase = blockIdx.y * 64;   // user dim
    const int tx = threadIdx.x, ty = threadIdx.y;
    const int x4 = tx * 4;

    float s[4], c[4];
    #pragma unroll
    for (int k = 0; k < 4; ++k) {
        const int y = ty + 16 * k;
        float4 v = *(const float4*)(R + (size_t)(rowBase + y) * N_ITEMS + colBase + x4);
        lds[y][x4 + 0] = v.x;
        lds[y][x4 + 1] = v.y;
        lds[y][x4 + 2] = v.z;
        lds[y][x4 + 3] = v.w;
        s[k] = v.x + v.y + v.z + v.w;
        c[k] = (v.x != 0.f) + (v.y != 0.f) + (v.z != 0.f) + (v.w != 0.f);
    }
    // reduce the 16 tx-lanes of each (ty,k) row group (lane = tx + 16*ty)
    #pragma unroll
    for (int k = 0; k < 4; ++k) {
        #pragma unroll
        for (int off = 8; off; off >>= 1) {
            s[k] += __shfl_down(s[k], off, 16);
            c[k] += __shfl_down(c[k], off, 16);
        }
    }
    if (tx == 0) {
        #pragma unroll
        for (int k = 0; k < 4; ++k) {
            const int u = rowBase + ty + 16 * k;
            psum[(size_t)blockIdx.x * N_USERS + u] = s[k];
            pcnt[(size_t)blockIdx.x * N_USERS + u] = c[k];
        }
    }
    __syncthreads();

    // store phase: 64 item-rows x 4 uchar16-chunks = 256 stores, 1 per thread
    const int tid = ty * 16 + tx;
    const int il = tid >> 2;              // local item row 0..63
    const int ch = tid & 3;               // user chunk (16 users)
    union { unsigned char b[16]; int4 v; } w;
    #pragma unroll
    for (int e = 0; e < 16; ++e) {
        w.b[e] = (unsigned char)(int)lds[ch * 16 + e][il];
    }
    *(int4*)(AT + (size_t)(colBase + il) * N_USERS + rowBase + ch * 16) = w.v;
}

// ---------------------------------------------------------------------------
// K_fin: ub[u] = cnt>0 ? sum/max(cnt,1) : 0   (reduce 64 tile-partials)
// 4-way segment split per user: 128 blocks x 256 thr = 512 waves.
// ---------------------------------------------------------------------------
__global__ __launch_bounds__(256) void k_fin(const float* __restrict__ psum,
                                             const float* __restrict__ pcnt,
                                             float* __restrict__ ub) {
    __shared__ float ss[4][64], sc[4][64];
    const int ul  = threadIdx.x & 63;
    const int seg = threadIdx.x >> 6;     // 0..3: which 16-tile segment
    const int u = blockIdx.x * 64 + ul;
    float s = 0.f, c = 0.f;
    #pragma unroll
    for (int k = 0; k < 16; ++k) {
        const int t = seg * 16 + k;
        s += psum[(size_t)t * N_USERS + u];
        c += pcnt[(size_t)t * N_USERS + u];
    }
    ss[seg][ul] = s;
    sc[seg][ul] = c;
    __syncthreads();
    if (seg == 0) {
        s = ss[0][ul] + ss[1][ul] + ss[2][ul] + ss[3][ul];
        c = sc[0][ul] + sc[1][ul] + sc[2][ul] + sc[3][ul];
        ub[u] = (c > 0.f) ? s / fmaxf(c, 1.f) : 0.f;
    }
}

// ---------------------------------------------------------------------------
// K_B: one WAVE per batch element, 8 waves (512 thr) per block.
//   out[b] = sigmoid( dot(S[user[b]], (float)AT[item[b]] - ub) + biases ) * 5
// ub staged into 32 KiB LDS once per block; 3 VMEM + 2 ds_read_b128 per iter.
// Grid BATCH/8 x 512thr. LDS 32KiB -> 4 blocks/CU (32 waves, full occupancy).
// ---------------------------------------------------------------------------
__global__ __launch_bounds__(512, 6) void k_main(const float* __restrict__ S,
                                                 const unsigned char* __restrict__ AT,
                                                 const float* __restrict__ ub,
                                                 const int* __restrict__ user,
                                                 const int* __restrict__ item,
                                                 const float* __restrict__ ubias,
                                                 const float* __restrict__ ibias,
                                                 const float* __restrict__ gbias,
                                                 float* __restrict__ out) {
    __shared__ float4 ubs[N_USERS / 4];   // 32 KiB
    #pragma unroll
    for (int t = 0; t < 4; ++t) {
        ubs[t * 512 + threadIdx.x] = ((const float4*)ub)[t * 512 + threadIdx.x];
    }
    __syncthreads();

    const int wave = threadIdx.x >> 6;
    const int lane = threadIdx.x & 63;
    const int b = blockIdx.x * 8 + wave;
    const int su = user[b];
    const int j  = item[b];
    const float4* srow = (const float4*)(S + (size_t)su * N_USERS);
    const uint2*  arow = (const uint2*)(AT + (size_t)j * N_USERS);

    float acc = 0.f;
    #pragma unroll 4
    for (int i = 0; i < 16; ++i) {
        const int idx = i * 64 + lane;       // unit = 8 users
        uint2  a  = arow[idx];
        float4 s0 = srow[2 * idx + 0];
        float4 s1 = srow[2 * idx + 1];
        float4 u0 = ubs[2 * idx + 0];
        float4 u1 = ubs[2 * idx + 1];
        acc += s0.x * ((float)( a.x        & 0xffu) - u0.x);
        acc += s0.y * ((float)((a.x >>  8) & 0xffu) - u0.y);
        acc += s0.z * ((float)((a.x >> 16) & 0xffu) - u0.z);
        acc += s0.w * ((float)( a.x >> 24         ) - u0.w);
        acc += s1.x * ((float)( a.y        & 0xffu) - u1.x);
        acc += s1.y * ((float)((a.y >>  8) & 0xffu) - u1.y);
        acc += s1.z * ((float)((a.y >> 16) & 0xffu) - u1.z);
        acc += s1.w * ((float)( a.y >> 24         ) - u1.w);
    }
    #pragma unroll
    for (int off = 32; off; off >>= 1) acc += __shfl_down(acc, off);

    if (lane == 0) {
        float score = acc + ubias[su] + ibias[j] + gbias[0];
        out[b] = 5.f / (1.f + expf(-score));
    }
}

// ---------------------------------------------------------------------------
// Fallback path (ws too small): original 3-pass f32 scheme.
// ---------------------------------------------------------------------------
__global__ __launch_bounds__(256) void k_ubfix(const float* __restrict__ R,
                                               float* __restrict__ ub) {
    const int wave = threadIdx.x >> 6;
    const int lane = threadIdx.x & 63;
    const int u = blockIdx.x * 4 + wave;
    const float4* row4 = (const float4*)(R + (size_t)u * N_ITEMS);
    float s = 0.f, c = 0.f;
    #pragma unroll
    for (int i = 0; i < 16; ++i) {
        float4 v = row4[i * 64 + lane];
        s += v.x + v.y + v.z + v.w;
        c += (v.x != 0.f) + (v.y != 0.f) + (v.z != 0.f) + (v.w != 0.f);
    }
    #pragma unroll
    for (int off = 32; off; off >>= 1) {
        s += __shfl_down(s, off);
        c += __shfl_down(c, off);
    }
    if (lane == 0)
        ub[u] = (c > 0.f) ? s / fmaxf(c, 1.f) : 0.f;
}

__global__ __launch_bounds__(256) void k_direct(const float* __restrict__ S,
                                                const float* __restrict__ R,
                                                const float* __restrict__ ub,
                                                const int* __restrict__ user,
                                                const int* __restrict__ item,
                                                const float* __restrict__ ubias,
                                                const float* __restrict__ ibias,
                                                const float* __restrict__ gbias,
                                                float* __restrict__ out) {
    const int b = blockIdx.x;
    const int su = user[b];
    const int j  = item[b];
    const float* srow = S + (size_t)su * N_USERS;
    float acc = 0.f;
    for (int u = threadIdx.x; u < N_USERS; u += 256) {
        acc += srow[u] * (R[(size_t)u * N_ITEMS + j] - ub[u]);
    }
    for (int off = 32; off; off >>= 1) acc += __shfl_down(acc, off);
    __shared__ float sa[4];
    const int lane = threadIdx.x & 63, w = threadIdx.x >> 6;
    if (lane == 0) sa[w] = acc;
    __syncthreads();
    if (threadIdx.x == 0) {
        float score = sa[0] + sa[1] + sa[2] + sa[3]
                    + ubias[su] + ibias[j] + gbias[0];
        out[b] = 5.f / (1.f + expf(-score));
    }
}

extern "C" void kernel_launch(void* const* d_in, const int* in_sizes, int n_in,
                              void* d_out, int out_size, void* d_ws, size_t ws_size,
                              hipStream_t stream) {
    const int*   user  = (const int*)d_in[0];
    const int*   item  = (const int*)d_in[1];
    const float* R     = (const float*)d_in[2];   // [N_USERS][N_ITEMS] f32
    const float* S     = (const float*)d_in[3];   // [N_USERS][N_USERS] f32
    const float* ubias = (const float*)d_in[4];
    const float* ibias = (const float*)d_in[5];
    const float* gbias = (const float*)d_in[6];
    float* out = (float*)d_out;

    // ws layout:
    //   [0, 32KB)            ub[N_USERS] f32
    //   [64KB, 64KB+2MB)     psum[NTILE_I][N_USERS] f32
    //   [64KB+2MB, +2MB)     pcnt[NTILE_I][N_USERS] f32
    //   [8MB, 8MB+33.5MB)    AT[N_ITEMS][N_USERS] uint8
    float* ub   = (float*)d_ws;
    float* psum = (float*)((char*)d_ws + (64u << 10));
    float* pcnt = (float*)((char*)d_ws + (64u << 10) + ((size_t)NTILE_I * N_USERS * 4));
    unsigned char* AT = (unsigned char*)((char*)d_ws + (8u << 20));
    const size_t need = (8u << 20) + (size_t)N_ITEMS * N_USERS;

    if (ws_size >= need) {
        dim3 tgrid(NTILE_I, N_USERS / 64);
        dim3 tblk(16, 16);
        k_trans<<<tgrid, tblk, 0, stream>>>(R, AT, psum, pcnt);
        k_fin<<<N_USERS / 64, 256, 0, stream>>>(psum, pcnt, ub);
        k_main<<<BATCH / 8, 512, 0, stream>>>(S, AT, ub, user, item, ubias, ibias, gbias, out);
    } else {
        k_ubfix<<<N_USERS / 4, 256, 0, stream>>>(R, ub);
        k_direct<<<BATCH, 256, 0, stream>>>(S, R, ub, user, item, ubias, ibias, gbias, out);
    }
}